// Round 3
// baseline (443.882 us; speedup 1.0000x reference)
//
#include <hip/hip_runtime.h>
#include <hip/hip_bf16.h>
#include <math.h>

#define B_   8
#define F_   4
#define S_   512
#define D_   256
#define H_   8
#define DK_  32
#define DV_  32
#define NBF  32                 // B*F
#define NROWS (NBF * S_)        // 16384
#define NG   (NBF * H_)         // 256 (b,f,h) groups
#define LN_EPS 1e-5f

typedef __attribute__((ext_vector_type(8))) short bf16x8;
typedef __attribute__((ext_vector_type(4))) float f32x4;

__device__ __forceinline__ short f2bf(float f) {
    union { float f; unsigned u; } v; v.f = f;
    unsigned u = v.u;
    u += 0x7FFFu + ((u >> 16) & 1u);   // round-to-nearest-even
    return (short)(u >> 16);
}

// ---------------------------------------------------------------------------
// Kernel 1: q/k/v projections, fused (unchanged this round).
// ---------------------------------------------------------------------------
__global__ __launch_bounds__(256) void qkv_kernel(
    const float* __restrict__ x,
    const float* __restrict__ Wq, const float* __restrict__ Wk,
    const float* __restrict__ Wv,
    float* __restrict__ qo, float* __restrict__ ko, float* __restrict__ vo)
{
    const int TM = 16;
    __shared__ float xs[TM][D_];
    const int r0 = blockIdx.x * TM;
    const int j  = threadIdx.x;

    for (int i = threadIdx.x; i < TM * D_ / 4; i += 256) {
        int r = i / (D_ / 4);
        int c = (i % (D_ / 4)) * 4;
        *(float4*)&xs[r][c] = *(const float4*)&x[(size_t)(r0 + r) * D_ + c];
    }
    __syncthreads();

    float aq[TM], ak[TM], av[TM];
#pragma unroll
    for (int r = 0; r < TM; ++r) { aq[r] = 0.f; ak[r] = 0.f; av[r] = 0.f; }

    for (int kk = 0; kk < D_; kk += 4) {
        float wq0 = Wq[(kk + 0) * D_ + j], wq1 = Wq[(kk + 1) * D_ + j];
        float wq2 = Wq[(kk + 2) * D_ + j], wq3 = Wq[(kk + 3) * D_ + j];
        float wk0 = Wk[(kk + 0) * D_ + j], wk1 = Wk[(kk + 1) * D_ + j];
        float wk2 = Wk[(kk + 2) * D_ + j], wk3 = Wk[(kk + 3) * D_ + j];
        float wv0 = Wv[(kk + 0) * D_ + j], wv1 = Wv[(kk + 1) * D_ + j];
        float wv2 = Wv[(kk + 2) * D_ + j], wv3 = Wv[(kk + 3) * D_ + j];
#pragma unroll
        for (int r = 0; r < TM; ++r) {
            float4 xv = *(const float4*)&xs[r][kk];
            aq[r] = fmaf(xv.x, wq0, aq[r]); aq[r] = fmaf(xv.y, wq1, aq[r]);
            aq[r] = fmaf(xv.z, wq2, aq[r]); aq[r] = fmaf(xv.w, wq3, aq[r]);
            ak[r] = fmaf(xv.x, wk0, ak[r]); ak[r] = fmaf(xv.y, wk1, ak[r]);
            ak[r] = fmaf(xv.z, wk2, ak[r]); ak[r] = fmaf(xv.w, wk3, ak[r]);
            av[r] = fmaf(xv.x, wv0, av[r]); av[r] = fmaf(xv.y, wv1, av[r]);
            av[r] = fmaf(xv.z, wv2, av[r]); av[r] = fmaf(xv.w, wv3, av[r]);
        }
    }
#pragma unroll
    for (int r = 0; r < TM; ++r) {
        qo[(size_t)(r0 + r) * D_ + j] = aq[r];
        ko[(size_t)(r0 + r) * D_ + j] = ak[r];
        vo[(size_t)(r0 + r) * D_ + j] = av[r];
    }
}

// ---------------------------------------------------------------------------
// Kernel 2: scores = QK^T/sqrt(32)+res via bf16 MFMA (K=32 in ONE mfma).
// Block = 512 thr = 8 waves; block covers 64 rows x 512 cols of one g.
// Wave w covers cols w*64..w*64+63 (4 col-tiles of 16), rows = 4 row-tiles.
// Per-column partial softmax stats (max, sumexp over the 64 rows) -> ws.
// ---------------------------------------------------------------------------
__global__ __launch_bounds__(512) void scores_kernel(
    const float* __restrict__ q, const float* __restrict__ k,
    const float* __restrict__ res, float* __restrict__ sc_out,
    float* __restrict__ pmax, float* __restrict__ psum)
{
    const int bid = blockIdx.x;
    const int g   = bid >> 3;         // (b,f,h)
    const int st  = bid & 7;          // row tile (64 rows)
    const int bf  = g >> 3;
    const int h   = g & 7;
    const size_t rowbase = (size_t)bf * S_ * D_ + (size_t)h * DK_;
    const size_t sbase   = (size_t)g * S_ * S_;
    const int s0   = st * 64;
    const int w    = threadIdx.x >> 6;
    const int lane = threadIdx.x & 63;
    const int lr   = lane & 15;       // fragment row/col within tile
    const int lg   = lane >> 4;       // k-group / D row group

    // A fragments: Q[s0+rt*16+lr][lg*8 .. +8)  (8 contiguous floats -> bf16)
    bf16x8 afrag[4];
#pragma unroll
    for (int rt = 0; rt < 4; ++rt) {
        const float* qp = &q[rowbase + (size_t)(s0 + rt * 16 + lr) * D_ + lg * 8];
        float4 q0 = *(const float4*)qp;
        float4 q1 = *(const float4*)(qp + 4);
        bf16x8 a;
        a[0] = f2bf(q0.x); a[1] = f2bf(q0.y); a[2] = f2bf(q0.z); a[3] = f2bf(q0.w);
        a[4] = f2bf(q1.x); a[5] = f2bf(q1.y); a[6] = f2bf(q1.z); a[7] = f2bf(q1.w);
        afrag[rt] = a;
    }

    const float scale = 0.17677669529663687f;  // 1/sqrt(32)
    const f32x4 zero = {0.f, 0.f, 0.f, 0.f};

#pragma unroll
    for (int ct = 0; ct < 4; ++ct) {
        const int t0 = w * 64 + ct * 16;
        // B fragment: B[k][t] = K[t0+lr][lg*8+j]
        const float* kp = &k[rowbase + (size_t)(t0 + lr) * D_ + lg * 8];
        float4 k0 = *(const float4*)kp;
        float4 k1 = *(const float4*)(kp + 4);
        bf16x8 b;
        b[0] = f2bf(k0.x); b[1] = f2bf(k0.y); b[2] = f2bf(k0.z); b[3] = f2bf(k0.w);
        b[4] = f2bf(k1.x); b[5] = f2bf(k1.y); b[6] = f2bf(k1.z); b[7] = f2bf(k1.w);

        f32x4 acc[4];
#pragma unroll
        for (int rt = 0; rt < 4; ++rt)
            acc[rt] = __builtin_amdgcn_mfma_f32_16x16x32_bf16(afrag[rt], b, zero, 0, 0, 0);

        // epilogue: scale, +res, write, collect 16 column-values in regs
        float sc[16];
#pragma unroll
        for (int rt = 0; rt < 4; ++rt) {
#pragma unroll
            for (int j = 0; j < 4; ++j) {
                const int row = s0 + rt * 16 + lg * 4 + j;
                const size_t off = sbase + (size_t)row * S_ + t0 + lr;
                float v = fmaf(acc[rt][j], scale, res[off]);
                sc_out[off] = v;
                sc[rt * 4 + j] = v;
            }
        }

        // per-lane two-pass stats over its 16 rows of column (t0+lr)
        float m = sc[0];
#pragma unroll
        for (int i = 1; i < 16; ++i) m = fmaxf(m, sc[i]);
        float z = 0.f;
#pragma unroll
        for (int i = 0; i < 16; ++i) z += __expf(sc[i] - m);

        // combine the 4 lanes (lg groups) holding the same column
#pragma unroll
        for (int off = 16; off <= 32; off <<= 1) {
            float om = __shfl_xor(m, off);
            float oz = __shfl_xor(z, off);
            float nm = fmaxf(m, om);
            z = z * __expf(m - nm) + oz * __expf(om - nm);
            m = nm;
        }
        if (lg == 0) {
            pmax[(size_t)bid * S_ + t0 + lr] = m;
            psum[(size_t)bid * S_ + t0 + lr] = z;
        }
    }
}

// ---------------------------------------------------------------------------
// Kernel 3: merge 8 partial stats per (g,t) -> global column max M, inv sum iZ
// ---------------------------------------------------------------------------
__global__ __launch_bounds__(256) void stats_kernel(
    const float* __restrict__ pmax, const float* __restrict__ psum,
    float* __restrict__ M, float* __restrict__ iZ)
{
    const int idx = blockIdx.x * 256 + threadIdx.x;   // g*512 + t
    const int g = idx >> 9;
    const int t = idx & 511;
    float m = -1e30f;
    float pm[8];
#pragma unroll
    for (int i = 0; i < 8; ++i) {
        pm[i] = pmax[((size_t)g * 8 + i) * S_ + t];
        m = fmaxf(m, pm[i]);
    }
    float z = 0.f;
#pragma unroll
    for (int i = 0; i < 8; ++i)
        z += psum[((size_t)g * 8 + i) * S_ + t] * __expf(pm[i] - m);
    M[idx]  = m;
    iZ[idx] = 1.f / z;
}

// ---------------------------------------------------------------------------
// Kernel 4: ctx[s,v] = sum_t exp(sc[s,t]-M[t])*iZ[t] * V[t,v]  (unchanged)
// ---------------------------------------------------------------------------
__global__ __launch_bounds__(256) void pv_kernel(
    const float* __restrict__ sc, const float* __restrict__ v,
    const float* __restrict__ M, const float* __restrict__ iZ,
    float* __restrict__ ctx)
{
    const int idx = (int)gridDim.x - 1 - (int)blockIdx.x;  // reverse order
    const int g  = idx >> 2;
    const int rt = idx & 3;
    const int bf = g >> 3;
    const int h  = g & 7;
    const size_t sbase = (size_t)g * S_ * S_;
    const size_t vrow  = (size_t)bf * S_ * D_ + (size_t)h * DV_;
    const int s0 = rt * 128;

    __shared__ float Ml[S_];
    __shared__ float iZl[S_];
    __shared__ float e_lds[128][65];
    __shared__ float v_lds[64][32];

    for (int i = threadIdx.x; i < S_; i += 256) {
        Ml[i]  = M[(size_t)g * S_ + i];
        iZl[i] = iZ[(size_t)g * S_ + i];
    }

    const int rslot = threadIdx.x >> 3;   // 0..31
    const int vq    = threadIdx.x & 7;    // 0..7

    float acc[4][4];
#pragma unroll
    for (int r = 0; r < 4; ++r)
#pragma unroll
        for (int j = 0; j < 4; ++j) acc[r][j] = 0.f;

    for (int tc = 0; tc < S_; tc += 64) {
        __syncthreads();
        for (int i = threadIdx.x; i < 128 * 16; i += 256) {
            int r  = i >> 4;
            int c4 = (i & 15) * 4;
            float4 s4 = *(const float4*)&sc[sbase + (size_t)(s0 + r) * S_ + tc + c4];
            e_lds[r][c4 + 0] = __expf(s4.x - Ml[tc + c4 + 0]) * iZl[tc + c4 + 0];
            e_lds[r][c4 + 1] = __expf(s4.y - Ml[tc + c4 + 1]) * iZl[tc + c4 + 1];
            e_lds[r][c4 + 2] = __expf(s4.z - Ml[tc + c4 + 2]) * iZl[tc + c4 + 2];
            e_lds[r][c4 + 3] = __expf(s4.w - Ml[tc + c4 + 3]) * iZl[tc + c4 + 3];
        }
        for (int i = threadIdx.x; i < 64 * 8; i += 256) {
            int r  = i >> 3;
            int c4 = (i & 7) * 4;
            *(float4*)&v_lds[r][c4] =
                *(const float4*)&v[vrow + (size_t)(tc + r) * D_ + c4];
        }
        __syncthreads();
        for (int tt = 0; tt < 64; tt += 4) {
            float4 vv0 = *(const float4*)&v_lds[tt + 0][vq * 4];
            float4 vv1 = *(const float4*)&v_lds[tt + 1][vq * 4];
            float4 vv2 = *(const float4*)&v_lds[tt + 2][vq * 4];
            float4 vv3 = *(const float4*)&v_lds[tt + 3][vq * 4];
#pragma unroll
            for (int rr = 0; rr < 4; ++rr) {
                float4 e4 = *(const float4*)&e_lds[rslot * 4 + rr][tt];
                acc[rr][0] = fmaf(e4.x, vv0.x, acc[rr][0]);
                acc[rr][1] = fmaf(e4.x, vv0.y, acc[rr][1]);
                acc[rr][2] = fmaf(e4.x, vv0.z, acc[rr][2]);
                acc[rr][3] = fmaf(e4.x, vv0.w, acc[rr][3]);
                acc[rr][0] = fmaf(e4.y, vv1.x, acc[rr][0]);
                acc[rr][1] = fmaf(e4.y, vv1.y, acc[rr][1]);
                acc[rr][2] = fmaf(e4.y, vv1.z, acc[rr][2]);
                acc[rr][3] = fmaf(e4.y, vv1.w, acc[rr][3]);
                acc[rr][0] = fmaf(e4.z, vv2.x, acc[rr][0]);
                acc[rr][1] = fmaf(e4.z, vv2.y, acc[rr][1]);
                acc[rr][2] = fmaf(e4.z, vv2.z, acc[rr][2]);
                acc[rr][3] = fmaf(e4.z, vv2.w, acc[rr][3]);
                acc[rr][0] = fmaf(e4.w, vv3.x, acc[rr][0]);
                acc[rr][1] = fmaf(e4.w, vv3.y, acc[rr][1]);
                acc[rr][2] = fmaf(e4.w, vv3.z, acc[rr][2]);
                acc[rr][3] = fmaf(e4.w, vv3.w, acc[rr][3]);
            }
        }
    }

#pragma unroll
    for (int rr = 0; rr < 4; ++rr) {
        float* crow = &ctx[((size_t)bf * S_ + s0 + rslot * 4 + rr) * D_
                           + (size_t)h * DV_ + vq * 4];
        float4 o;
        o.x = acc[rr][0]; o.y = acc[rr][1]; o.z = acc[rr][2]; o.w = acc[rr][3];
        *(float4*)crow = o;
    }
}

// ---------------------------------------------------------------------------
// Kernel 5: out = LayerNorm(ctx @ W_fc + x) * g + b   (unchanged)
// ---------------------------------------------------------------------------
__global__ __launch_bounds__(256) void out_kernel(
    const float* __restrict__ ctx, const float* __restrict__ x,
    const float* __restrict__ Wfc, const float* __restrict__ gam,
    const float* __restrict__ bet, float* __restrict__ out)
{
    const int TM = 16;
    __shared__ float cs[TM][D_];
    __shared__ float red[TM][4][2];
    const int r0 = blockIdx.x * TM;
    const int j  = threadIdx.x;

    for (int i = threadIdx.x; i < TM * D_ / 4; i += 256) {
        int r = i / (D_ / 4);
        int c = (i % (D_ / 4)) * 4;
        *(float4*)&cs[r][c] = *(const float4*)&ctx[(size_t)(r0 + r) * D_ + c];
    }
    __syncthreads();

    float y[TM];
#pragma unroll
    for (int r = 0; r < TM; ++r) y[r] = 0.f;

    for (int kk = 0; kk < D_; kk += 4) {
        float w0 = Wfc[(kk + 0) * D_ + j], w1 = Wfc[(kk + 1) * D_ + j];
        float w2 = Wfc[(kk + 2) * D_ + j], w3 = Wfc[(kk + 3) * D_ + j];
#pragma unroll
        for (int r = 0; r < TM; ++r) {
            float4 c4 = *(const float4*)&cs[r][kk];
            y[r] = fmaf(c4.x, w0, y[r]); y[r] = fmaf(c4.y, w1, y[r]);
            y[r] = fmaf(c4.z, w2, y[r]); y[r] = fmaf(c4.w, w3, y[r]);
        }
    }
#pragma unroll
    for (int r = 0; r < TM; ++r) y[r] += x[(size_t)(r0 + r) * D_ + j];

    const int lane = threadIdx.x & 63;
    const int w    = threadIdx.x >> 6;
#pragma unroll
    for (int r = 0; r < TM; ++r) {
        float s1 = y[r], s2 = y[r] * y[r];
        for (int off = 32; off; off >>= 1) {
            s1 += __shfl_xor(s1, off);
            s2 += __shfl_xor(s2, off);
        }
        if (lane == 0) { red[r][w][0] = s1; red[r][w][1] = s2; }
    }
    __syncthreads();

#pragma unroll
    for (int r = 0; r < TM; ++r) {
        float s1 = red[r][0][0] + red[r][1][0] + red[r][2][0] + red[r][3][0];
        float s2 = red[r][0][1] + red[r][1][1] + red[r][2][1] + red[r][3][1];
        float mu  = s1 * (1.f / D_);
        float var = s2 * (1.f / D_) - mu * mu;
        float o = (y[r] - mu) * rsqrtf(var + LN_EPS) * gam[j] + bet[j];
        out[(size_t)(r0 + r) * D_ + j] = o;
    }
}

extern "C" void kernel_launch(void* const* d_in, const int* in_sizes, int n_in,
                              void* d_out, int out_size, void* d_ws, size_t ws_size,
                              hipStream_t stream)
{
    const float* x   = (const float*)d_in[0];
    const float* res = (const float*)d_in[1];
    const float* Wq  = (const float*)d_in[2];
    const float* Wk  = (const float*)d_in[3];
    const float* Wv  = (const float*)d_in[4];
    const float* Wfc = (const float*)d_in[5];
    const float* gam = (const float*)d_in[6];
    const float* bet = (const float*)d_in[7];

    float* out    = (float*)d_out;
    float* scores = out + (size_t)NROWS * D_;   // output 1 after output 0

    float* q    = (float*)d_ws;
    float* k    = q    + (size_t)NROWS * D_;
    float* v    = k    + (size_t)NROWS * D_;
    float* ctx  = v    + (size_t)NROWS * D_;
    float* pmax = ctx  + (size_t)NROWS * D_;
    float* psum = pmax + (size_t)NG * 8 * S_;
    float* M    = psum + (size_t)NG * 8 * S_;
    float* iZ   = M    + (size_t)NG * S_;

    qkv_kernel<<<dim3(NROWS / 16), 256, 0, stream>>>(x, Wq, Wk, Wv, q, k, v);
    scores_kernel<<<dim3(NG * 8), 512, 0, stream>>>(q, k, res, scores, pmax, psum);
    stats_kernel<<<dim3(NG * S_ / 256), 256, 0, stream>>>(pmax, psum, M, iZ);
    pv_kernel<<<dim3(NG * 4), 256, 0, stream>>>(scores, v, M, iZ, ctx);
    out_kernel<<<dim3(NROWS / 16), 256, 0, stream>>>(ctx, x, Wfc, gam, bet, out);
}

// Round 5
// 370.337 us; speedup vs baseline: 1.1986x; 1.1986x over previous
//
#include <hip/hip_runtime.h>
#include <math.h>

#define B_   8
#define F_   4
#define S_   512
#define D_   256
#define H_   8
#define DK_  32
#define DV_  32
#define NBF  32                 // B*F
#define NROWS (NBF * S_)        // 16384
#define NG   (NBF * H_)         // 256 (b,f,h) groups
#define LN_EPS 1e-5f

typedef __attribute__((ext_vector_type(8))) short bf16x8;
typedef __attribute__((ext_vector_type(4))) float f32x4;
typedef __attribute__((ext_vector_type(8))) unsigned short u16x8;

__device__ __forceinline__ short f2bf(float f) {
    union { float f; unsigned u; } v; v.f = f;
    unsigned u = v.u;
    u += 0x7FFFu + ((u >> 16) & 1u);   // round-to-nearest-even
    return (short)(u >> 16);
}

__device__ __forceinline__ bf16x8 pack8(float4 a, float4 b) {
    bf16x8 r;
    r[0] = f2bf(a.x); r[1] = f2bf(a.y); r[2] = f2bf(a.z); r[3] = f2bf(a.w);
    r[4] = f2bf(b.x); r[5] = f2bf(b.y); r[6] = f2bf(b.z); r[7] = f2bf(b.w);
    return r;
}

union BFU { u16x8 u; bf16x8 b; };

// ---------------------------------------------------------------------------
// Kernel 0: pack Wq,Wk,Wv into MFMA B-fragment order, bf16 (no UB: vector
// built element-wise).  Wp[((wsel*8+ks)*16+ct)*64 + lane][j] =
//   W[ks*32 + (lane>>4)*8 + j][ct*16 + (lane&15)]
// ---------------------------------------------------------------------------
__global__ __launch_bounds__(64) void wpack_kernel(
    const float* __restrict__ Wq, const float* __restrict__ Wk,
    const float* __restrict__ Wv,
    unsigned short* __restrict__ Wp)
{
    const int bid  = blockIdx.x;           // (wsel*8+ks)*16+ct, 384 blocks
    const int ct   = bid & 15;
    const int ks   = (bid >> 4) & 7;
    const int wsel = bid >> 7;
    const float* W = (wsel == 0) ? Wq : (wsel == 1) ? Wk : Wv;
    const int lane = threadIdx.x;
    const int lr = lane & 15, lg = lane >> 4;
    u16x8 t;
#pragma unroll
    for (int j = 0; j < 8; ++j)
        t[j] = (unsigned short)f2bf(W[(ks * 32 + lg * 8 + j) * 256 + ct * 16 + lr]);
    *(u16x8*)(Wp + ((size_t)bid * 64 + lane) * 8) = t;
}

// ---------------------------------------------------------------------------
// Kernel 1: q/k/v projections via bf16 MFMA.  grid 768: rowblk = bid&255,
// wsel = bid>>8.  Block 256 thr = 4 waves; wave = 16 rows x 256 cols.
// ---------------------------------------------------------------------------
__global__ __launch_bounds__(256) void qkv_kernel(
    const float* __restrict__ x, const unsigned short* __restrict__ Wp,
    float* __restrict__ qo, float* __restrict__ ko, float* __restrict__ vo)
{
    const int bid    = blockIdx.x;
    const int rowblk = bid & 255;
    const int wsel   = bid >> 8;
    float* outp = (wsel == 0) ? qo : (wsel == 1) ? ko : vo;
    const int m0   = rowblk * 64;
    const int w    = threadIdx.x >> 6;
    const int lane = threadIdx.x & 63;
    const int lr = lane & 15, lg = lane >> 4;
    const int arow = m0 + w * 16 + lr;

    const f32x4 zero = {0.f, 0.f, 0.f, 0.f};
    f32x4 acc[16];
#pragma unroll
    for (int ct = 0; ct < 16; ++ct) acc[ct] = zero;

    for (int ks = 0; ks < 8; ++ks) {
        const float* xp = &x[(size_t)arow * 256 + ks * 32 + lg * 8];
        bf16x8 a = pack8(*(const float4*)xp, *(const float4*)(xp + 4));
        const u16x8* wp = (const u16x8*)(Wp + ((size_t)(wsel * 8 + ks) * 16) * 64 * 8);
#pragma unroll
        for (int ct = 0; ct < 16; ++ct) {
            BFU bb; bb.u = wp[ct * 64 + lane];
            acc[ct] = __builtin_amdgcn_mfma_f32_16x16x32_bf16(a, bb.b, acc[ct], 0, 0, 0);
        }
    }
#pragma unroll
    for (int ct = 0; ct < 16; ++ct)
#pragma unroll
        for (int j = 0; j < 4; ++j)
            outp[(size_t)(m0 + w * 16 + lg * 4 + j) * 256 + ct * 16 + lr] = acc[ct][j];
}

// ---------------------------------------------------------------------------
// Kernel 2: scores = QK^T/sqrt(32)+res via MFMA, streaming IO through an LDS
// tile; per-column partial softmax stats.  grid 4096: g = bid&255,
// st = (bid>>8)>>1 (64-row tile), ch = (bid>>8)&1 (256-col chunk).
// Block 512 thr = 8 waves; block = 64 rows x 256 cols.
// ---------------------------------------------------------------------------
__global__ __launch_bounds__(512) void scores_kernel(
    const float* __restrict__ q, const float* __restrict__ k,
    const float* __restrict__ res, float* __restrict__ sc_out,
    float* __restrict__ pmax, float* __restrict__ psum)
{
    const int bid  = blockIdx.x;
    const int g    = bid & 255;
    const int stch = bid >> 8;         // 0..15
    const int st   = stch >> 1;
    const int ch   = stch & 1;
    const int bf = g >> 3, h = g & 7;
    const size_t qkbase = (size_t)bf * S_ * D_ + (size_t)h * 32;
    const size_t sbase  = (size_t)g * S_ * S_;
    const int s0 = st * 64, c0 = ch * 256;

    __shared__ float T[64][260];
    const int tid = threadIdx.x;

    // phase 1: res tile -> LDS (1KB contiguous per wave-load)
#pragma unroll
    for (int p = 0; p < 8; ++p) {
        int idx = tid + p * 512;
        int r = idx >> 6, c4 = (idx & 63) * 4;
        *(float4*)&T[r][c4] =
            *(const float4*)&res[sbase + (size_t)(s0 + r) * S_ + c0 + c4];
    }
    __syncthreads();

    const int w = tid >> 6, lane = tid & 63;
    const int lr = lane & 15, lg = lane >> 4;

    // A fragments: Q rows (all waves use the same 64 rows)
    bf16x8 afrag[4];
#pragma unroll
    for (int rt = 0; rt < 4; ++rt) {
        const float* qp = &q[qkbase + (size_t)(s0 + rt * 16 + lr) * D_ + lg * 8];
        afrag[rt] = pack8(*(const float4*)qp, *(const float4*)(qp + 4));
    }

    const float scale = 0.17677669529663687f;  // 1/sqrt(32)
    const f32x4 zero = {0.f, 0.f, 0.f, 0.f};

#pragma unroll
    for (int ctl = 0; ctl < 2; ++ctl) {
        const int lcol = w * 32 + ctl * 16 + lr;  // column within the 256 chunk
        const int tcol = c0 + lcol;               // global column (t)
        const float* kp = &k[qkbase + (size_t)tcol * D_ + lg * 8];
        bf16x8 b = pack8(*(const float4*)kp, *(const float4*)(kp + 4));

        f32x4 accr[4];
#pragma unroll
        for (int rt = 0; rt < 4; ++rt)
            accr[rt] = __builtin_amdgcn_mfma_f32_16x16x32_bf16(afrag[rt], b, zero, 0, 0, 0);

        float sc[16];
#pragma unroll
        for (int rt = 0; rt < 4; ++rt)
#pragma unroll
            for (int j = 0; j < 4; ++j) {
                const int r = rt * 16 + lg * 4 + j;
                float v = fmaf(accr[rt][j], scale, T[r][lcol]);
                T[r][lcol] = v;
                sc[rt * 4 + j] = v;
            }
        float m = sc[0];
#pragma unroll
        for (int i = 1; i < 16; ++i) m = fmaxf(m, sc[i]);
        float z = 0.f;
#pragma unroll
        for (int i = 0; i < 16; ++i) z += __expf(sc[i] - m);
#pragma unroll
        for (int off = 16; off <= 32; off <<= 1) {
            float om = __shfl_xor(m, off);
            float oz = __shfl_xor(z, off);
            float nm = fmaxf(m, om);
            z = z * __expf(m - nm) + oz * __expf(om - nm);
            m = nm;
        }
        if (lg == 0) {
            pmax[((size_t)g * 8 + st) * S_ + tcol] = m;
            psum[((size_t)g * 8 + st) * S_ + tcol] = z;
        }
    }
    __syncthreads();

    // phase 3: LDS -> sc_out (1KB contiguous per wave-store)
#pragma unroll
    for (int p = 0; p < 8; ++p) {
        int idx = tid + p * 512;
        int r = idx >> 6, c4 = (idx & 63) * 4;
        *(float4*)&sc_out[sbase + (size_t)(s0 + r) * S_ + c0 + c4] =
            *(float4*)&T[r][c4];
    }
}

// ---------------------------------------------------------------------------
// Kernel 3: merge 8 partial stats per (g,t) -> column max M, inv sum iZ
// ---------------------------------------------------------------------------
__global__ __launch_bounds__(256) void stats_kernel(
    const float* __restrict__ pmax, const float* __restrict__ psum,
    float* __restrict__ M, float* __restrict__ iZ)
{
    const int idx = blockIdx.x * 256 + threadIdx.x;   // g*512 + t
    const int g = idx >> 9;
    const int t = idx & 511;
    float m = -1e30f;
    float pm[8];
#pragma unroll
    for (int i = 0; i < 8; ++i) {
        pm[i] = pmax[((size_t)g * 8 + i) * S_ + t];
        m = fmaxf(m, pm[i]);
    }
    float z = 0.f;
#pragma unroll
    for (int i = 0; i < 8; ++i)
        z += psum[((size_t)g * 8 + i) * S_ + t] * __expf(pm[i] - m);
    M[idx]  = m;
    iZ[idx] = 1.f / z;
}

// ---------------------------------------------------------------------------
// Kernel 4 (round-2 proven scalar): ctx = attn-weighted V.
// ---------------------------------------------------------------------------
__global__ __launch_bounds__(256) void pv_kernel(
    const float* __restrict__ sc, const float* __restrict__ v,
    const float* __restrict__ M, const float* __restrict__ iZ,
    float* __restrict__ ctx)
{
    const int idx = (int)gridDim.x - 1 - (int)blockIdx.x;  // reverse order
    const int g  = idx >> 2;
    const int rt = idx & 3;
    const int bf = g >> 3;
    const int h  = g & 7;
    const size_t sbase = (size_t)g * S_ * S_;
    const size_t vrow  = (size_t)bf * S_ * D_ + (size_t)h * DV_;
    const int s0 = rt * 128;

    __shared__ float Ml[S_];
    __shared__ float iZl[S_];
    __shared__ float e_lds[128][65];
    __shared__ float v_lds[64][32];

    for (int i = threadIdx.x; i < S_; i += 256) {
        Ml[i]  = M[(size_t)g * S_ + i];
        iZl[i] = iZ[(size_t)g * S_ + i];
    }

    const int rslot = threadIdx.x >> 3;   // 0..31
    const int vq    = threadIdx.x & 7;    // 0..7

    float acc[4][4];
#pragma unroll
    for (int r = 0; r < 4; ++r)
#pragma unroll
        for (int j = 0; j < 4; ++j) acc[r][j] = 0.f;

    for (int tc = 0; tc < S_; tc += 64) {
        __syncthreads();
        for (int i = threadIdx.x; i < 128 * 16; i += 256) {
            int r  = i >> 4;
            int c4 = (i & 15) * 4;
            float4 s4 = *(const float4*)&sc[sbase + (size_t)(s0 + r) * S_ + tc + c4];
            e_lds[r][c4 + 0] = __expf(s4.x - Ml[tc + c4 + 0]) * iZl[tc + c4 + 0];
            e_lds[r][c4 + 1] = __expf(s4.y - Ml[tc + c4 + 1]) * iZl[tc + c4 + 1];
            e_lds[r][c4 + 2] = __expf(s4.z - Ml[tc + c4 + 2]) * iZl[tc + c4 + 2];
            e_lds[r][c4 + 3] = __expf(s4.w - Ml[tc + c4 + 3]) * iZl[tc + c4 + 3];
        }
        for (int i = threadIdx.x; i < 64 * 8; i += 256) {
            int r  = i >> 3;
            int c4 = (i & 7) * 4;
            *(float4*)&v_lds[r][c4] =
                *(const float4*)&v[vrow + (size_t)(tc + r) * D_ + c4];
        }
        __syncthreads();
        for (int tt = 0; tt < 64; tt += 4) {
            float4 vv0 = *(const float4*)&v_lds[tt + 0][vq * 4];
            float4 vv1 = *(const float4*)&v_lds[tt + 1][vq * 4];
            float4 vv2 = *(const float4*)&v_lds[tt + 2][vq * 4];
            float4 vv3 = *(const float4*)&v_lds[tt + 3][vq * 4];
#pragma unroll
            for (int rr = 0; rr < 4; ++rr) {
                float4 e4 = *(const float4*)&e_lds[rslot * 4 + rr][tt];
                acc[rr][0] = fmaf(e4.x, vv0.x, acc[rr][0]);
                acc[rr][1] = fmaf(e4.x, vv0.y, acc[rr][1]);
                acc[rr][2] = fmaf(e4.x, vv0.z, acc[rr][2]);
                acc[rr][3] = fmaf(e4.x, vv0.w, acc[rr][3]);
                acc[rr][0] = fmaf(e4.y, vv1.x, acc[rr][0]);
                acc[rr][1] = fmaf(e4.y, vv1.y, acc[rr][1]);
                acc[rr][2] = fmaf(e4.y, vv1.z, acc[rr][2]);
                acc[rr][3] = fmaf(e4.y, vv1.w, acc[rr][3]);
                acc[rr][0] = fmaf(e4.z, vv2.x, acc[rr][0]);
                acc[rr][1] = fmaf(e4.z, vv2.y, acc[rr][1]);
                acc[rr][2] = fmaf(e4.z, vv2.z, acc[rr][2]);
                acc[rr][3] = fmaf(e4.z, vv2.w, acc[rr][3]);
                acc[rr][0] = fmaf(e4.w, vv3.x, acc[rr][0]);
                acc[rr][1] = fmaf(e4.w, vv3.y, acc[rr][1]);
                acc[rr][2] = fmaf(e4.w, vv3.z, acc[rr][2]);
                acc[rr][3] = fmaf(e4.w, vv3.w, acc[rr][3]);
            }
        }
    }

#pragma unroll
    for (int rr = 0; rr < 4; ++rr) {
        float* crow = &ctx[((size_t)bf * S_ + s0 + rslot * 4 + rr) * D_
                           + (size_t)h * DV_ + vq * 4];
        float4 o;
        o.x = acc[rr][0]; o.y = acc[rr][1]; o.z = acc[rr][2]; o.w = acc[rr][3];
        *(float4*)crow = o;
    }
}

// ---------------------------------------------------------------------------
// Kernel 5 (round-2 proven scalar): out = LayerNorm(ctx @ W_fc + x) * g + b
// ---------------------------------------------------------------------------
__global__ __launch_bounds__(256) void out_kernel(
    const float* __restrict__ ctx, const float* __restrict__ x,
    const float* __restrict__ Wfc, const float* __restrict__ gam,
    const float* __restrict__ bet, float* __restrict__ out)
{
    const int TM = 16;
    __shared__ float cs[TM][D_];
    __shared__ float red[TM][4][2];
    const int r0 = blockIdx.x * TM;
    const int j  = threadIdx.x;

    for (int i = threadIdx.x; i < TM * D_ / 4; i += 256) {
        int r = i / (D_ / 4);
        int c = (i % (D_ / 4)) * 4;
        *(float4*)&cs[r][c] = *(const float4*)&ctx[(size_t)(r0 + r) * D_ + c];
    }
    __syncthreads();

    float y[TM];
#pragma unroll
    for (int r = 0; r < TM; ++r) y[r] = 0.f;

    for (int kk = 0; kk < D_; kk += 4) {
        float w0 = Wfc[(kk + 0) * D_ + j], w1 = Wfc[(kk + 1) * D_ + j];
        float w2 = Wfc[(kk + 2) * D_ + j], w3 = Wfc[(kk + 3) * D_ + j];
#pragma unroll
        for (int r = 0; r < TM; ++r) {
            float4 c4 = *(const float4*)&cs[r][kk];
            y[r] = fmaf(c4.x, w0, y[r]); y[r] = fmaf(c4.y, w1, y[r]);
            y[r] = fmaf(c4.z, w2, y[r]); y[r] = fmaf(c4.w, w3, y[r]);
        }
    }
#pragma unroll
    for (int r = 0; r < TM; ++r) y[r] += x[(size_t)(r0 + r) * D_ + j];

    const int lane = threadIdx.x & 63;
    const int w    = threadIdx.x >> 6;
#pragma unroll
    for (int r = 0; r < TM; ++r) {
        float s1 = y[r], s2 = y[r] * y[r];
        for (int off = 32; off; off >>= 1) {
            s1 += __shfl_xor(s1, off);
            s2 += __shfl_xor(s2, off);
        }
        if (lane == 0) { red[r][w][0] = s1; red[r][w][1] = s2; }
    }
    __syncthreads();

#pragma unroll
    for (int r = 0; r < TM; ++r) {
        float s1 = red[r][0][0] + red[r][1][0] + red[r][2][0] + red[r][3][0];
        float s2 = red[r][0][1] + red[r][1][1] + red[r][2][1] + red[r][3][1];
        float mu  = s1 * (1.f / D_);
        float var = s2 * (1.f / D_) - mu * mu;
        float o = (y[r] - mu) * rsqrtf(var + LN_EPS) * gam[j] + bet[j];
        out[(size_t)(r0 + r) * D_ + j] = o;
    }
}

extern "C" void kernel_launch(void* const* d_in, const int* in_sizes, int n_in,
                              void* d_out, int out_size, void* d_ws, size_t ws_size,
                              hipStream_t stream)
{
    const float* x   = (const float*)d_in[0];
    const float* res = (const float*)d_in[1];
    const float* Wq  = (const float*)d_in[2];
    const float* Wk  = (const float*)d_in[3];
    const float* Wv  = (const float*)d_in[4];
    const float* Wfc = (const float*)d_in[5];
    const float* gam = (const float*)d_in[6];
    const float* bet = (const float*)d_in[7];

    float* out    = (float*)d_out;
    float* scores = out + (size_t)NROWS * D_;   // output 1 after output 0

    // ws layout identical to the proven round-2/3 footprint (73 MiB).
    // Wp ALIASES the ctx buffer: consumed by qkv_kernel before pv writes ctx.
    float* q    = (float*)d_ws;
    float* k    = q    + (size_t)NROWS * D_;
    float* v    = k    + (size_t)NROWS * D_;
    float* ctx  = v    + (size_t)NROWS * D_;
    float* pmax = ctx  + (size_t)NROWS * D_;
    float* psum = pmax + (size_t)NG * 8 * S_;
    float* M    = psum + (size_t)NG * 8 * S_;
    float* iZ   = M    + (size_t)NG * S_;
    unsigned short* Wp = (unsigned short*)ctx;  // 0.75 MB inside 16 MB ctx buf

    wpack_kernel<<<dim3(384), 64, 0, stream>>>(Wq, Wk, Wv, Wp);
    qkv_kernel<<<dim3(768), 256, 0, stream>>>(x, Wp, q, k, v);
    scores_kernel<<<dim3(4096), 512, 0, stream>>>(q, k, res, scores, pmax, psum);
    stats_kernel<<<dim3(NG * S_ / 256), 256, 0, stream>>>(pmax, psum, M, iZ);
    pv_kernel<<<dim3(NG * 4), 256, 0, stream>>>(scores, v, M, iZ, ctx);
    out_kernel<<<dim3(NROWS / 16), 256, 0, stream>>>(ctx, x, Wfc, gam, bet, out);
}

// Round 7
// 299.562 us; speedup vs baseline: 1.4818x; 1.2363x over previous
//
#include <hip/hip_runtime.h>
#include <math.h>

#define B_   8
#define F_   4
#define S_   512
#define D_   256
#define H_   8
#define DK_  32
#define DV_  32
#define NBF  32                 // B*F
#define NROWS (NBF * S_)        // 16384
#define NG   (NBF * H_)         // 256 (b,f,h) groups
#define LN_EPS 1e-5f

typedef __attribute__((ext_vector_type(8))) short bf16x8;
typedef __attribute__((ext_vector_type(4))) float f32x4;
typedef __attribute__((ext_vector_type(8))) unsigned short u16x8;

__device__ __forceinline__ short f2bf(float f) {
    union { float f; unsigned u; } v; v.f = f;
    unsigned u = v.u;
    u += 0x7FFFu + ((u >> 16) & 1u);   // round-to-nearest-even
    return (short)(u >> 16);
}

__device__ __forceinline__ bf16x8 pack8(float4 a, float4 b) {
    bf16x8 r;
    r[0] = f2bf(a.x); r[1] = f2bf(a.y); r[2] = f2bf(a.z); r[3] = f2bf(a.w);
    r[4] = f2bf(b.x); r[5] = f2bf(b.y); r[6] = f2bf(b.z); r[7] = f2bf(b.w);
    return r;
}

union BFU { u16x8 u; bf16x8 b; };

// ---------------------------------------------------------------------------
// Kernel 0 (round-5 verbatim): pack Wq,Wk,Wv into MFMA B-fragment order.
// Wp[((wsel*8+ks)*16+ct)*64 + lane][j] = W[ks*32+(lane>>4)*8+j][ct*16+(lane&15)]
// ---------------------------------------------------------------------------
__global__ __launch_bounds__(64) void wpack_kernel(
    const float* __restrict__ Wq, const float* __restrict__ Wk,
    const float* __restrict__ Wv,
    unsigned short* __restrict__ Wp)
{
    const int bid  = blockIdx.x;           // (wsel*8+ks)*16+ct, 384 blocks
    const int ct   = bid & 15;
    const int ks   = (bid >> 4) & 7;
    const int wsel = bid >> 7;
    const float* W = (wsel == 0) ? Wq : (wsel == 1) ? Wk : Wv;
    const int lane = threadIdx.x;
    const int lr = lane & 15, lg = lane >> 4;
    u16x8 t;
#pragma unroll
    for (int j = 0; j < 8; ++j)
        t[j] = (unsigned short)f2bf(W[(ks * 32 + lg * 8 + j) * 256 + ct * 16 + lr]);
    *(u16x8*)(Wp + ((size_t)bid * 64 + lane) * 8) = t;
}

// ---------------------------------------------------------------------------
// Kernel 1 (round-5 verbatim): q/k/v projections via bf16 MFMA, fp32 outputs.
// ---------------------------------------------------------------------------
__global__ __launch_bounds__(256) void qkv_kernel(
    const float* __restrict__ x, const unsigned short* __restrict__ Wp,
    float* __restrict__ qo, float* __restrict__ ko, float* __restrict__ vo)
{
    const int bid    = blockIdx.x;
    const int rowblk = bid & 255;
    const int wsel   = bid >> 8;
    float* outp = (wsel == 0) ? qo : (wsel == 1) ? ko : vo;
    const int m0   = rowblk * 64;
    const int w    = threadIdx.x >> 6;
    const int lane = threadIdx.x & 63;
    const int lr = lane & 15, lg = lane >> 4;
    const int arow = m0 + w * 16 + lr;

    const f32x4 zero = {0.f, 0.f, 0.f, 0.f};
    f32x4 acc[16];
#pragma unroll
    for (int ct = 0; ct < 16; ++ct) acc[ct] = zero;

    for (int ks = 0; ks < 8; ++ks) {
        const float* xp = &x[(size_t)arow * 256 + ks * 32 + lg * 8];
        bf16x8 a = pack8(*(const float4*)xp, *(const float4*)(xp + 4));
        const u16x8* wp = (const u16x8*)(Wp + ((size_t)(wsel * 8 + ks) * 16) * 64 * 8);
#pragma unroll
        for (int ct = 0; ct < 16; ++ct) {
            BFU bb; bb.u = wp[ct * 64 + lane];
            acc[ct] = __builtin_amdgcn_mfma_f32_16x16x32_bf16(a, bb.b, acc[ct], 0, 0, 0);
        }
    }
#pragma unroll
    for (int ct = 0; ct < 16; ++ct)
#pragma unroll
        for (int j = 0; j < 4; ++j)
            outp[(size_t)(m0 + w * 16 + lg * 4 + j) * 256 + ct * 16 + lr] = acc[ct][j];
}

// ---------------------------------------------------------------------------
// Kernel 2 (round-5 verbatim): scores = QK^T/sqrt(32)+res via MFMA, LDS tile.
// ---------------------------------------------------------------------------
__global__ __launch_bounds__(512) void scores_kernel(
    const float* __restrict__ q, const float* __restrict__ k,
    const float* __restrict__ res, float* __restrict__ sc_out,
    float* __restrict__ pmax, float* __restrict__ psum)
{
    const int bid  = blockIdx.x;
    const int g    = bid & 255;
    const int stch = bid >> 8;         // 0..15
    const int st   = stch >> 1;
    const int ch   = stch & 1;
    const int bf = g >> 3, h = g & 7;
    const size_t qkbase = (size_t)bf * S_ * D_ + (size_t)h * 32;
    const size_t sbase  = (size_t)g * S_ * S_;
    const int s0 = st * 64, c0 = ch * 256;

    __shared__ float T[64][260];
    const int tid = threadIdx.x;

#pragma unroll
    for (int p = 0; p < 8; ++p) {
        int idx = tid + p * 512;
        int r = idx >> 6, c4 = (idx & 63) * 4;
        *(float4*)&T[r][c4] =
            *(const float4*)&res[sbase + (size_t)(s0 + r) * S_ + c0 + c4];
    }
    __syncthreads();

    const int w = tid >> 6, lane = tid & 63;
    const int lr = lane & 15, lg = lane >> 4;

    bf16x8 afrag[4];
#pragma unroll
    for (int rt = 0; rt < 4; ++rt) {
        const float* qp = &q[qkbase + (size_t)(s0 + rt * 16 + lr) * D_ + lg * 8];
        afrag[rt] = pack8(*(const float4*)qp, *(const float4*)(qp + 4));
    }

    const float scale = 0.17677669529663687f;  // 1/sqrt(32)
    const f32x4 zero = {0.f, 0.f, 0.f, 0.f};

#pragma unroll
    for (int ctl = 0; ctl < 2; ++ctl) {
        const int lcol = w * 32 + ctl * 16 + lr;
        const int tcol = c0 + lcol;
        const float* kp = &k[qkbase + (size_t)tcol * D_ + lg * 8];
        bf16x8 b = pack8(*(const float4*)kp, *(const float4*)(kp + 4));

        f32x4 accr[4];
#pragma unroll
        for (int rt = 0; rt < 4; ++rt)
            accr[rt] = __builtin_amdgcn_mfma_f32_16x16x32_bf16(afrag[rt], b, zero, 0, 0, 0);

        float sc[16];
#pragma unroll
        for (int rt = 0; rt < 4; ++rt)
#pragma unroll
            for (int j = 0; j < 4; ++j) {
                const int r = rt * 16 + lg * 4 + j;
                float v = fmaf(accr[rt][j], scale, T[r][lcol]);
                T[r][lcol] = v;
                sc[rt * 4 + j] = v;
            }
        float m = sc[0];
#pragma unroll
        for (int i = 1; i < 16; ++i) m = fmaxf(m, sc[i]);
        float z = 0.f;
#pragma unroll
        for (int i = 0; i < 16; ++i) z += __expf(sc[i] - m);
#pragma unroll
        for (int off = 16; off <= 32; off <<= 1) {
            float om = __shfl_xor(m, off);
            float oz = __shfl_xor(z, off);
            float nm = fmaxf(m, om);
            z = z * __expf(m - nm) + oz * __expf(om - nm);
            m = nm;
        }
        if (lg == 0) {
            pmax[((size_t)g * 8 + st) * S_ + tcol] = m;
            psum[((size_t)g * 8 + st) * S_ + tcol] = z;
        }
    }
    __syncthreads();

#pragma unroll
    for (int p = 0; p < 8; ++p) {
        int idx = tid + p * 512;
        int r = idx >> 6, c4 = (idx & 63) * 4;
        *(float4*)&sc_out[sbase + (size_t)(s0 + r) * S_ + c0 + c4] =
            *(float4*)&T[r][c4];
    }
}

// ---------------------------------------------------------------------------
// Kernel 3 (round-5 verbatim): merge 8 partial stats -> M, iZ
// ---------------------------------------------------------------------------
__global__ __launch_bounds__(256) void stats_kernel(
    const float* __restrict__ pmax, const float* __restrict__ psum,
    float* __restrict__ M, float* __restrict__ iZ)
{
    const int idx = blockIdx.x * 256 + threadIdx.x;   // g*512 + t
    const int g = idx >> 9;
    const int t = idx & 511;
    float m = -1e30f;
    float pm[8];
#pragma unroll
    for (int i = 0; i < 8; ++i) {
        pm[i] = pmax[((size_t)g * 8 + i) * S_ + t];
        m = fmaxf(m, pm[i]);
    }
    float z = 0.f;
#pragma unroll
    for (int i = 0; i < 8; ++i)
        z += psum[((size_t)g * 8 + i) * S_ + t] * __expf(pm[i] - m);
    M[idx]  = m;
    iZ[idx] = 1.f / z;
}

// ---------------------------------------------------------------------------
// Kernel 4 (THE single change this round): ctx = attn @ V via bf16 MFMA.
// grid 2048: g = bid&255, rt = 7-(bid>>8).  Block 256 thr = 4 waves;
// wave = 16 rows x 32 v-cols; 16 K-steps of 32.
// ---------------------------------------------------------------------------
__global__ __launch_bounds__(256) void pv_kernel(
    const float* __restrict__ sc, const float* __restrict__ v,
    const float* __restrict__ M, const float* __restrict__ iZ,
    float* __restrict__ ctx)
{
    const int bid = blockIdx.x;
    const int g   = bid & 255;
    const int rt  = 7 - (bid >> 8);
    const int bf = g >> 3, h = g & 7;
    const size_t sbase = (size_t)g * S_ * S_;

    __shared__ unsigned short VT[32][520];   // V^T bf16: VT[vcol][t]
    __shared__ float Ml[S_];
    __shared__ float iZl[S_];
    const int tid = threadIdx.x;

    for (int i = tid; i < S_; i += 256) {
        Ml[i]  = M[(size_t)g * S_ + i];
        iZl[i] = iZ[(size_t)g * S_ + i];
    }
    for (int i = tid; i < S_ * 8; i += 256) {
        int t = i >> 3, v4 = (i & 7) * 4;
        float4 vv = *(const float4*)&v[((size_t)bf * S_ + t) * D_ + h * 32 + v4];
        VT[v4 + 0][t] = (unsigned short)f2bf(vv.x);
        VT[v4 + 1][t] = (unsigned short)f2bf(vv.y);
        VT[v4 + 2][t] = (unsigned short)f2bf(vv.z);
        VT[v4 + 3][t] = (unsigned short)f2bf(vv.w);
    }
    __syncthreads();

    const int w = tid >> 6, lane = tid & 63;
    const int lr = lane & 15, lg = lane >> 4;
    const int srow = rt * 64 + w * 16 + lr;

    const f32x4 zero = {0.f, 0.f, 0.f, 0.f};
    f32x4 acc[2] = {zero, zero};

    for (int kt = 0; kt < 16; ++kt) {
        const int t0 = kt * 32 + lg * 8;
        const float* sp = &sc[sbase + (size_t)srow * S_ + t0];
        float4 sa = *(const float4*)sp;
        float4 sb = *(const float4*)(sp + 4);
        bf16x8 a;
        a[0] = f2bf(__expf(sa.x - Ml[t0 + 0]) * iZl[t0 + 0]);
        a[1] = f2bf(__expf(sa.y - Ml[t0 + 1]) * iZl[t0 + 1]);
        a[2] = f2bf(__expf(sa.z - Ml[t0 + 2]) * iZl[t0 + 2]);
        a[3] = f2bf(__expf(sa.w - Ml[t0 + 3]) * iZl[t0 + 3]);
        a[4] = f2bf(__expf(sb.x - Ml[t0 + 4]) * iZl[t0 + 4]);
        a[5] = f2bf(__expf(sb.y - Ml[t0 + 5]) * iZl[t0 + 5]);
        a[6] = f2bf(__expf(sb.z - Ml[t0 + 6]) * iZl[t0 + 6]);
        a[7] = f2bf(__expf(sb.w - Ml[t0 + 7]) * iZl[t0 + 7]);
#pragma unroll
        for (int ct = 0; ct < 2; ++ct) {
            BFU bb;
            bb.u = *(u16x8*)&VT[ct * 16 + lr][kt * 32 + lg * 8];
            acc[ct] = __builtin_amdgcn_mfma_f32_16x16x32_bf16(a, bb.b, acc[ct], 0, 0, 0);
        }
    }
#pragma unroll
    for (int ct = 0; ct < 2; ++ct)
#pragma unroll
        for (int j = 0; j < 4; ++j)
            ctx[((size_t)bf * S_ + rt * 64 + w * 16 + lg * 4 + j) * D_
                + h * 32 + ct * 16 + lr] = acc[ct][j];
}

// ---------------------------------------------------------------------------
// Kernel 5 (round-5 verbatim scalar): out = LayerNorm(ctx @ W_fc + x) * g + b
// ---------------------------------------------------------------------------
__global__ __launch_bounds__(256) void out_kernel(
    const float* __restrict__ ctx, const float* __restrict__ x,
    const float* __restrict__ Wfc, const float* __restrict__ gam,
    const float* __restrict__ bet, float* __restrict__ out)
{
    const int TM = 16;
    __shared__ float cs[TM][D_];
    __shared__ float red[TM][4][2];
    const int r0 = blockIdx.x * TM;
    const int j  = threadIdx.x;

    for (int i = threadIdx.x; i < TM * D_ / 4; i += 256) {
        int r = i / (D_ / 4);
        int c = (i % (D_ / 4)) * 4;
        *(float4*)&cs[r][c] = *(const float4*)&ctx[(size_t)(r0 + r) * D_ + c];
    }
    __syncthreads();

    float y[TM];
#pragma unroll
    for (int r = 0; r < TM; ++r) y[r] = 0.f;

    for (int kk = 0; kk < D_; kk += 4) {
        float w0 = Wfc[(kk + 0) * D_ + j], w1 = Wfc[(kk + 1) * D_ + j];
        float w2 = Wfc[(kk + 2) * D_ + j], w3 = Wfc[(kk + 3) * D_ + j];
#pragma unroll
        for (int r = 0; r < TM; ++r) {
            float4 c4 = *(const float4*)&cs[r][kk];
            y[r] = fmaf(c4.x, w0, y[r]); y[r] = fmaf(c4.y, w1, y[r]);
            y[r] = fmaf(c4.z, w2, y[r]); y[r] = fmaf(c4.w, w3, y[r]);
        }
    }
#pragma unroll
    for (int r = 0; r < TM; ++r) y[r] += x[(size_t)(r0 + r) * D_ + j];

    const int lane = threadIdx.x & 63;
    const int w    = threadIdx.x >> 6;
#pragma unroll
    for (int r = 0; r < TM; ++r) {
        float s1 = y[r], s2 = y[r] * y[r];
        for (int off = 32; off; off >>= 1) {
            s1 += __shfl_xor(s1, off);
            s2 += __shfl_xor(s2, off);
        }
        if (lane == 0) { red[r][w][0] = s1; red[r][w][1] = s2; }
    }
    __syncthreads();

#pragma unroll
    for (int r = 0; r < TM; ++r) {
        float s1 = red[r][0][0] + red[r][1][0] + red[r][2][0] + red[r][3][0];
        float s2 = red[r][0][1] + red[r][1][1] + red[r][2][1] + red[r][3][1];
        float mu  = s1 * (1.f / D_);
        float var = s2 * (1.f / D_) - mu * mu;
        float o = (y[r] - mu) * rsqrtf(var + LN_EPS) * gam[j] + bet[j];
        out[(size_t)(r0 + r) * D_ + j] = o;
    }
}

extern "C" void kernel_launch(void* const* d_in, const int* in_sizes, int n_in,
                              void* d_out, int out_size, void* d_ws, size_t ws_size,
                              hipStream_t stream)
{
    const float* x   = (const float*)d_in[0];
    const float* res = (const float*)d_in[1];
    const float* Wq  = (const float*)d_in[2];
    const float* Wk  = (const float*)d_in[3];
    const float* Wv  = (const float*)d_in[4];
    const float* Wfc = (const float*)d_in[5];
    const float* gam = (const float*)d_in[6];
    const float* bet = (const float*)d_in[7];

    float* out    = (float*)d_out;
    float* scores = out + (size_t)NROWS * D_;   // output 1 after output 0

    // ws layout identical to round 5 (passed).  Wp aliases ctx (consumed by
    // qkv_kernel before pv writes ctx).
    float* q    = (float*)d_ws;
    float* k    = q    + (size_t)NROWS * D_;
    float* v    = k    + (size_t)NROWS * D_;
    float* ctx  = v    + (size_t)NROWS * D_;
    float* pmax = ctx  + (size_t)NROWS * D_;
    float* psum = pmax + (size_t)NG * 8 * S_;
    float* M    = psum + (size_t)NG * 8 * S_;
    float* iZ   = M    + (size_t)NG * S_;
    unsigned short* Wp = (unsigned short*)ctx;  // 0.75 MB inside 16 MB ctx buf

    wpack_kernel<<<dim3(384), 64, 0, stream>>>(Wq, Wk, Wv, Wp);
    qkv_kernel<<<dim3(768), 256, 0, stream>>>(x, Wp, q, k, v);
    scores_kernel<<<dim3(4096), 512, 0, stream>>>(q, k, res, scores, pmax, psum);
    stats_kernel<<<dim3(NG * S_ / 256), 256, 0, stream>>>(pmax, psum, M, iZ);
    pv_kernel<<<dim3(2048), 256, 0, stream>>>(scores, v, M, iZ, ctx);
    out_kernel<<<dim3(NROWS / 16), 256, 0, stream>>>(ctx, x, Wfc, gam, bet, out);
}